// Round 6
// baseline (497.595 us; speedup 1.0000x reference)
//
#include <hip/hip_runtime.h>

#define Bq 2
#define Nq 1024
#define Cq 128
#define Eq 64
#define Kq 20
#define BNK (Bq * Nq * Kq)
#define NEGF (-3.0e38f)
// Profiling reps (idempotent; removed next round once counters are read)
#define PROJ_REP 32
#define SCORE_REP 8
#define TOPK_REP 16

#define DPP_F(x, ctrl) __int_as_float(__builtin_amdgcn_update_dpp( \
    __float_as_int(x), __float_as_int(x), (ctrl), 0xf, 0xf, false))
#define DPP_I(x, ctrl) __builtin_amdgcn_update_dpp((x), (x), (ctrl), 0xf, 0xf, false)
#define RL_F(x, l) __int_as_float(__builtin_amdgcn_readlane(__float_as_int(x), (l)))
#define RL_I(x, l) __builtin_amdgcn_readlane((x), (l))
#define QP_XOR1 0xB1
#define QP_XOR2 0x4E
#define ROR4    0x124
#define ROR8    0x128

// ---------------- Kernel A: projections + rdot (R1 shape) ----------------
__global__ __launch_bounds__(128) void proj_kernel(
    const float* __restrict__ x, const float* __restrict__ Wl,
    const float* __restrict__ bl, const float* __restrict__ Wr,
    const float* __restrict__ br, const float* __restrict__ att,
    float* __restrict__ xl, float* __restrict__ xrT, float* __restrict__ rdot) {
  const int row = blockIdx.x;
  const int t = threadIdx.x;
  const int e = t & 63;
  const bool left = (t < 64);
  __shared__ float xs[Cq];
  for (int rep = 0; rep < PROJ_REP; ++rep) {
    xs[t] = x[(size_t)row * Cq + t];
    __syncthreads();
    const float* __restrict__ W = left ? Wl : Wr;
    float acc = 0.f;
#pragma unroll 8
    for (int c = 0; c < Cq; ++c) acc = fmaf(xs[c], W[c * Eq + e], acc);
    acc += left ? bl[e] : br[e];
    if (left) {
      xl[(size_t)row * Eq + e] = acc;
    } else {
      xrT[(size_t)e * (Bq * Nq) + row] = acc;
      float s = acc * att[e];
      s += DPP_F(s, QP_XOR1);
      s += DPP_F(s, QP_XOR2);
      s += DPP_F(s, ROR4);
      s += DPP_F(s, ROR8);
      const float sd = (RL_F(s, 0) + RL_F(s, 16)) + (RL_F(s, 32) + RL_F(s, 48));
      if (e == 0) rdot[row] = sd;
    }
    __syncthreads();
    asm volatile("" ::: "memory");
  }
}

// ---------------- Kernel B1: score -> alphaG in global ws ----------------
// grid 1024, block 256 (4 waves). 2 rows/block, thread = 4 consecutive j.
// LDS ~0.5KB -> 4 blocks/CU co-resident = 4 waves/SIMD.
__global__ __launch_bounds__(256) void score_kernel(
    const float* __restrict__ xl, const float* __restrict__ xrT,
    const float* __restrict__ rdot, const float* __restrict__ att,
    float* __restrict__ alphaG) {
  const int gi0 = blockIdx.x * 2;
  const int b   = gi0 >> 10;
  const int tid = threadIdx.x;
  __shared__ float xls2[2][Eq];
  for (int rep = 0; rep < SCORE_REP; ++rep) {
    if (tid < 2 * Eq) xls2[tid >> 6][tid & 63] = xl[(size_t)gi0 * Eq + tid];
    __syncthreads();
    const int j0 = tid * 4;
    const float4 rd4 = *(const float4*)&rdot[b * Nq + j0];
    float acc0[4] = {1.5f * rd4.x, 1.5f * rd4.y, 1.5f * rd4.z, 1.5f * rd4.w};
    float acc1[4] = {acc0[0], acc0[1], acc0[2], acc0[3]};
    const float* __restrict__ xrb = xrT + (size_t)b * Nq + j0;
#pragma unroll
    for (int ch = 0; ch < 16; ++ch) {
      const float4 av4 = *(const float4*)&att[ch * 4];
      const float4 xla = *(const float4*)&xls2[0][ch * 4];
      const float4 xlb = *(const float4*)&xls2[1][ch * 4];
      const float av[4] = {av4.x, av4.y, av4.z, av4.w};
      const float la[4] = {xla.x, xla.y, xla.z, xla.w};
      const float lb[4] = {xlb.x, xlb.y, xlb.z, xlb.w};
#pragma unroll
      for (int dd = 0; dd < 4; ++dd) {
        const float4 xv4 = *(const float4*)&xrb[(size_t)(ch * 4 + dd) * (Bq * Nq)];
        const float xv[4] = {xv4.x, xv4.y, xv4.z, xv4.w};
        const float a = av[dd];
#pragma unroll
        for (int jj = 0; jj < 4; ++jj) {
          acc0[jj] = fmaf(fabsf(la[dd] + xv[jj]), a, acc0[jj]);
          acc1[jj] = fmaf(fabsf(lb[dd] + xv[jj]), a, acc1[jj]);
        }
      }
    }
    *(float4*)&alphaG[(size_t)gi0 * Nq + j0] =
        make_float4(acc0[0], acc0[1], acc0[2], acc0[3]);
    *(float4*)&alphaG[(size_t)(gi0 + 1) * Nq + j0] =
        make_float4(acc1[0], acc1[1], acc1[2], acc1[3]);
    __syncthreads();
    asm volatile("" ::: "memory");
  }
}

// ---------------- Kernel B2: top-K + softmax from alphaG ----------------
// grid 512, block 256 (4 waves): wave owns one row.
__global__ __launch_bounds__(256) void topk_kernel(
    const float* __restrict__ alphaG, float* __restrict__ out) {
  const int row  = blockIdx.x * 4 + (threadIdx.x >> 6);
  const int lane = threadIdx.x & 63;
  const int b    = row >> 10;
  for (int rep = 0; rep < TOPK_REP; ++rep) {
    float vals[16];
#pragma unroll
    for (int s = 0; s < 16; ++s) vals[s] = alphaG[(size_t)row * Nq + lane + 64 * s];

    float lv = vals[0];
    int   pk = lane;
#pragma unroll
    for (int s = 1; s < 16; ++s)
      if (vals[s] > lv) { lv = vals[s]; pk = (s << 6) | lane; }

    float m0 = 0.f, ssum = 0.f, myv = 0.f;
    int myi = 0;
#pragma unroll 1
    for (int round = 0; round < Kq; ++round) {
      float m = lv;
      m = fmaxf(m, DPP_F(m, QP_XOR1));
      m = fmaxf(m, DPP_F(m, QP_XOR2));
      m = fmaxf(m, DPP_F(m, ROR4));
      m = fmaxf(m, DPP_F(m, ROR8));
      const float bv = fmaxf(fmaxf(RL_F(m, 0), RL_F(m, 16)),
                             fmaxf(RL_F(m, 32), RL_F(m, 48)));
      int key = (lv == bv) ? pk : 0x7FFFFFFF;
      key = min(key, DPP_I(key, QP_XOR1));
      key = min(key, DPP_I(key, QP_XOR2));
      key = min(key, DPP_I(key, ROR4));
      key = min(key, DPP_I(key, ROR8));
      const int jsel = min(min(RL_I(key, 0), RL_I(key, 16)),
                           min(RL_I(key, 32), RL_I(key, 48)));
      if (round == 0) m0 = bv;
      ssum += __expf(0.4f * (bv - m0));
      if (lane == round) { myv = bv; myi = jsel; }
      if (lane == (jsel & 63)) {
        const int sk = jsel >> 6;
#pragma unroll
        for (int s = 0; s < 16; ++s)
          if (s == sk) vals[s] = NEGF;
        lv = vals[0]; pk = lane;
#pragma unroll
        for (int s = 1; s < 16; ++s)
          if (vals[s] > lv) { lv = vals[s]; pk = (s << 6) | lane; }
      }
    }

    if (lane < Kq) {
      const float p = __expf(0.4f * (myv - m0)) / ssum;
      const int base = row * Kq + lane;
      out[base]            = (float)row;
      out[BNK + base]      = (float)(b * Nq + myi);
      out[2 * BNK + base]  = p;
    }
    asm volatile("" ::: "memory");
  }
}

extern "C" void kernel_launch(void* const* d_in, const int* in_sizes, int n_in,
                              void* d_out, int out_size, void* d_ws, size_t ws_size,
                              hipStream_t stream) {
  const float* x   = (const float*)d_in[0];
  const float* Wl  = (const float*)d_in[1];
  const float* bl  = (const float*)d_in[2];
  const float* Wr  = (const float*)d_in[3];
  const float* br  = (const float*)d_in[4];
  const float* att = (const float*)d_in[5];
  float* out = (float*)d_out;

  float* xl     = (float*)d_ws;                      // [B*N, E]
  float* xrT    = xl + (size_t)Bq * Nq * Eq;         // [E, B*N]
  float* rdot   = xrT + (size_t)Eq * Bq * Nq;        // [B*N]
  float* alphaG = rdot + (size_t)Bq * Nq;            // [B*N, N] = 8 MB

  proj_kernel<<<Bq * Nq, 128, 0, stream>>>(x, Wl, bl, Wr, br, att, xl, xrT, rdot);
  score_kernel<<<Bq * Nq / 2, 256, 0, stream>>>(xl, xrT, rdot, att, alphaG);
  topk_kernel<<<Bq * Nq / 4, 256, 0, stream>>>(alphaG, out);
}

// Round 7
// 48.851 us; speedup vs baseline: 10.1860x; 10.1860x over previous
//
#include <hip/hip_runtime.h>

#define Bq 2
#define Nq 1024
#define Cq 128
#define Eq 64
#define Kq 20
#define TI 8
#define BNK (Bq * Nq * Kq)
#define NEGF (-3.0e38f)

#define DPP_F(x, ctrl) __int_as_float(__builtin_amdgcn_update_dpp( \
    __float_as_int(x), __float_as_int(x), (ctrl), 0xf, 0xf, false))
#define DPP_I(x, ctrl) __builtin_amdgcn_update_dpp((x), (x), (ctrl), 0xf, 0xf, false)
#define RL_F(x, l) __int_as_float(__builtin_amdgcn_readlane(__float_as_int(x), (l)))
#define RL_I(x, l) __builtin_amdgcn_readlane((x), (l))
#define QP_XOR1 0xB1   // quad_perm [1,0,3,2]
#define QP_XOR2 0x4E   // quad_perm [2,3,0,1]
#define ROR4    0x124  // row_ror:4
#define ROR8    0x128  // row_ror:8

// ---------------- Kernel A: projections + rdot (R1 shape: 1 row/block) ----------------
// grid = B*N, block = 128 (2 waves), 8 blocks/CU -> 4 waves/SIMD, W L1-resident.
__global__ __launch_bounds__(128) void proj_kernel(
    const float* __restrict__ x, const float* __restrict__ Wl,
    const float* __restrict__ bl, const float* __restrict__ Wr,
    const float* __restrict__ br, const float* __restrict__ att,
    float* __restrict__ xl, float* __restrict__ xrT, float* __restrict__ rdot) {
  const int row = blockIdx.x;
  const int t = threadIdx.x;
  const int e = t & 63;
  const bool left = (t < 64);
  __shared__ float xs[Cq];
  xs[t] = x[(size_t)row * Cq + t];
  __syncthreads();
  const float* __restrict__ W = left ? Wl : Wr;
  float acc = 0.f;
#pragma unroll 8
  for (int c = 0; c < Cq; ++c) acc = fmaf(xs[c], W[c * Eq + e], acc);
  acc += left ? bl[e] : br[e];
  if (left) {
    xl[(size_t)row * Eq + e] = acc;
  } else {
    xrT[(size_t)e * (Bq * Nq) + row] = acc;
    float s = acc * att[e];                 // rdot[row] = sum_e xr[row][e]*att[e]
    s += DPP_F(s, QP_XOR1);
    s += DPP_F(s, QP_XOR2);
    s += DPP_F(s, ROR4);
    s += DPP_F(s, ROR8);
    const float sd = (RL_F(s, 0) + RL_F(s, 16)) + (RL_F(s, 32) + RL_F(s, 48));
    if (e == 0) rdot[row] = sd;
  }
}

// ---------------- Kernel B: fused scores + top-K, register-pressure-controlled ----------------
// block = 1024 (16 waves), grid = 256 (1 block/CU) -> 4 waves/SIMD.
// Phase 1: thread = (rgroup of 2 rows: (tid>>8)*2) x (4 consecutive j: (tid&255)*4).
// ch-loop unroll capped at 4 to keep <=16 float4 loads in flight (VGPR ~80, no spill).
__global__ __launch_bounds__(1024) void attn_kernel(
    const float* __restrict__ xl, const float* __restrict__ xrT,
    const float* __restrict__ rdot, const float* __restrict__ att,
    float* __restrict__ out) {
  const int gi0  = blockIdx.x * TI;
  const int b    = gi0 >> 10;
  const int tid  = threadIdx.x;
  const int lane = tid & 63;
  const int wave = tid >> 6;

  __shared__ float alpha[TI][Nq];   // 32 KB
  __shared__ float xls[TI][Eq];     // 2 KB

  if (tid < TI * Eq) xls[tid >> 6][tid & 63] = xl[(size_t)gi0 * Eq + tid];
  __syncthreads();

  // ---- phase 1: alphaS[r][j] = 1.5*rdot[j] + sum_d att[d]*|xl[r][d]+xr[j][d]| ----
  {
    const int jt = tid & 255;
    const int j0 = jt * 4;
    const int r0 = (tid >> 8) * 2;          // rows r0, r0+1
    const float4 rd4 = *(const float4*)&rdot[b * Nq + j0];
    float acc0[4], acc1[4];
    acc0[0] = 1.5f * rd4.x; acc0[1] = 1.5f * rd4.y;
    acc0[2] = 1.5f * rd4.z; acc0[3] = 1.5f * rd4.w;
    acc1[0] = acc0[0]; acc1[1] = acc0[1]; acc1[2] = acc0[2]; acc1[3] = acc0[3];

    const float* __restrict__ xrb = xrT + (size_t)b * Nq + j0;
#pragma unroll 4
    for (int ch = 0; ch < 16; ++ch) {
      const float4 av4 = *(const float4*)&att[ch * 4];            // uniform
      const float4 xla = *(const float4*)&xls[r0][ch * 4];        // LDS broadcast
      const float4 xlb = *(const float4*)&xls[r0 + 1][ch * 4];
      const float av[4]  = {av4.x, av4.y, av4.z, av4.w};
      const float la[4]  = {xla.x, xla.y, xla.z, xla.w};
      const float lb[4]  = {xlb.x, xlb.y, xlb.z, xlb.w};
#pragma unroll
      for (int dd = 0; dd < 4; ++dd) {
        const float4 xv4 = *(const float4*)&xrb[(size_t)(ch * 4 + dd) * (Bq * Nq)];
        const float xv[4] = {xv4.x, xv4.y, xv4.z, xv4.w};
        const float a = av[dd];
#pragma unroll
        for (int jj = 0; jj < 4; ++jj) {
          acc0[jj] = fmaf(fabsf(la[dd] + xv[jj]), a, acc0[jj]);
          acc1[jj] = fmaf(fabsf(lb[dd] + xv[jj]), a, acc1[jj]);
        }
      }
    }
    *(float4*)&alpha[r0][j0]     = make_float4(acc0[0], acc0[1], acc0[2], acc0[3]);
    *(float4*)&alpha[r0 + 1][j0] = make_float4(acc1[0], acc1[1], acc1[2], acc1[3]);
  }
  __syncthreads();

  // ---- phase 2: waves 0..7 = top-K of row `wave`, DPP-only reduces ----
  if (wave < TI) {
    float vals[16];
#pragma unroll
    for (int s = 0; s < 16; ++s) vals[s] = alpha[wave][lane + 64 * s];

    float lv = vals[0];
    int   pk = lane;                      // pk = (s<<6)|lane == j
#pragma unroll
    for (int s = 1; s < 16; ++s)
      if (vals[s] > lv) { lv = vals[s]; pk = (s << 6) | lane; }

    float m0 = 0.f, ssum = 0.f, myv = 0.f;
    int myi = 0;
#pragma unroll 1
    for (int round = 0; round < Kq; ++round) {
      float m = lv;
      m = fmaxf(m, DPP_F(m, QP_XOR1));
      m = fmaxf(m, DPP_F(m, QP_XOR2));
      m = fmaxf(m, DPP_F(m, ROR4));
      m = fmaxf(m, DPP_F(m, ROR8));
      const float bv = fmaxf(fmaxf(RL_F(m, 0), RL_F(m, 16)),
                             fmaxf(RL_F(m, 32), RL_F(m, 48)));
      int key = (lv == bv) ? pk : 0x7FFFFFFF;   // min-j tie-break (lax.top_k)
      key = min(key, DPP_I(key, QP_XOR1));
      key = min(key, DPP_I(key, QP_XOR2));
      key = min(key, DPP_I(key, ROR4));
      key = min(key, DPP_I(key, ROR8));
      const int jsel = min(min(RL_I(key, 0), RL_I(key, 16)),
                           min(RL_I(key, 32), RL_I(key, 48)));
      if (round == 0) m0 = bv;
      ssum += __expf(0.4f * (bv - m0));
      if (lane == round) { myv = bv; myi = jsel; }
      if (lane == (jsel & 63)) {          // owner knockout + rescan
        const int sk = jsel >> 6;
#pragma unroll
        for (int s = 0; s < 16; ++s)
          if (s == sk) vals[s] = NEGF;
        lv = vals[0]; pk = lane;
#pragma unroll
        for (int s = 1; s < 16; ++s)
          if (vals[s] > lv) { lv = vals[s]; pk = (s << 6) | lane; }
      }
    }

    if (lane < Kq) {
      const int gi = gi0 + wave;
      const float p = __expf(0.4f * (myv - m0)) / ssum;
      const int base = gi * Kq + lane;
      out[base]            = (float)gi;              // index_i
      out[BNK + base]      = (float)(b * Nq + myi);  // index_j
      out[2 * BNK + base]  = p;                      // attention
    }
  }
}

extern "C" void kernel_launch(void* const* d_in, const int* in_sizes, int n_in,
                              void* d_out, int out_size, void* d_ws, size_t ws_size,
                              hipStream_t stream) {
  const float* x   = (const float*)d_in[0];
  const float* Wl  = (const float*)d_in[1];
  const float* bl  = (const float*)d_in[2];
  const float* Wr  = (const float*)d_in[3];
  const float* br  = (const float*)d_in[4];
  const float* att = (const float*)d_in[5];
  float* out = (float*)d_out;

  float* xl   = (float*)d_ws;                    // [B*N, E]
  float* xrT  = xl + (size_t)Bq * Nq * Eq;       // [E, B*N]
  float* rdot = xrT + (size_t)Eq * Bq * Nq;      // [B*N]

  proj_kernel<<<Bq * Nq, 128, 0, stream>>>(x, Wl, bl, Wr, br, att, xl, xrT, rdot);
  attn_kernel<<<(Bq * Nq) / TI, 1024, 0, stream>>>(xl, xrT, rdot, att, out);
}

// Round 8
// 39.434 us; speedup vs baseline: 12.6184x; 1.2388x over previous
//
#include <hip/hip_runtime.h>

#define Bq 2
#define Nq 1024
#define Cq 128
#define Eq 64
#define Kq 20
#define TI 8
#define BN (Bq * Nq)
#define BNK (Bq * Nq * Kq)
#define NEGF (-3.0e38f)

#define DPP_F(x, ctrl) __int_as_float(__builtin_amdgcn_update_dpp( \
    __float_as_int(x), __float_as_int(x), (ctrl), 0xf, 0xf, false))
#define DPP_I(x, ctrl) __builtin_amdgcn_update_dpp((x), (x), (ctrl), 0xf, 0xf, false)
#define RL_F(x, l) __int_as_float(__builtin_amdgcn_readlane(__float_as_int(x), (l)))
#define RL_I(x, l) __builtin_amdgcn_readlane((x), (l))
#define QP_XOR1 0xB1   // quad_perm [1,0,3,2]
#define QP_XOR2 0x4E   // quad_perm [2,3,0,1]
#define ROR4    0x124  // row_ror:4
#define ROR8    0x128  // row_ror:8

// ---------------- Kernel A: projections + rdot; xr stored plane-major packed ----------------
// grid = B*N, block = 128 (2 waves). Wave 0 -> Wl (xl row), wave 1 -> Wr (xrP + rdot).
__global__ __launch_bounds__(128) void proj_kernel(
    const float* __restrict__ x, const float* __restrict__ Wl,
    const float* __restrict__ bl, const float* __restrict__ Wr,
    const float* __restrict__ br, const float* __restrict__ att,
    float* __restrict__ xl, float* __restrict__ xrP, float* __restrict__ rdot) {
  const int row = blockIdx.x;
  const int t = threadIdx.x;
  const int e = t & 63;
  const bool left = (t < 64);
  __shared__ float xs[Cq];
  xs[t] = x[(size_t)row * Cq + t];
  __syncthreads();
  const float* __restrict__ W = left ? Wl : Wr;
  float acc = 0.f;
#pragma unroll 8
  for (int c = 0; c < Cq; ++c) acc = fmaf(xs[c], W[c * Eq + e], acc);
  acc += left ? bl[e] : br[e];
  if (left) {
    xl[(size_t)row * Eq + e] = acc;
  } else {
    // plane-major: xrP[ch=e>>2][row][c=e&3]
    xrP[((size_t)(e >> 2) * BN + row) * 4 + (e & 3)] = acc;
    float s = acc * att[e];                 // rdot[row] = sum_e xr[row][e]*att[e]
    s += DPP_F(s, QP_XOR1);
    s += DPP_F(s, QP_XOR2);
    s += DPP_F(s, ROR4);
    s += DPP_F(s, ROR8);
    const float sd = (RL_F(s, 0) + RL_F(s, 16)) + (RL_F(s, 32) + RL_F(s, 48));
    if (e == 0) rdot[row] = sd;
  }
}

// ---------------- Kernel B: fused scores + top-K, explicit 1-ahead pipeline ----------------
// block = 1024 (16 waves), grid = 256. Thread tile: 4 rows x 2 j (j = jt, jt+512).
// xl/att consumed via wave-uniform scalar loads (readfirstlane'd row group).
__global__ __launch_bounds__(1024) void attn_kernel(
    const float* __restrict__ xl, const float* __restrict__ xrP,
    const float* __restrict__ rdot, const float* __restrict__ att,
    float* __restrict__ out) {
  const int gi0  = blockIdx.x * TI;
  const int b    = gi0 >> 10;
  const int tid  = threadIdx.x;
  const int lane = tid & 63;
  const int wave = tid >> 6;

  __shared__ float alpha[TI][Nq];   // 32 KB

  // ---- phase 1 ----
  {
    const int jt = tid & 511;
    const int r0 = __builtin_amdgcn_readfirstlane(tid >> 9) * 4;  // wave-uniform
    const float* __restrict__ vb  = xrP + (size_t)(b * Nq + jt) * 4;
    const float* __restrict__ xlw = xl + (size_t)(gi0 + r0) * Eq; // uniform -> s_load

    const float rd0 = 1.5f * rdot[b * Nq + jt];
    const float rd1 = 1.5f * rdot[b * Nq + jt + 512];
    float acc[4][2];
#pragma unroll
    for (int r = 0; r < 4; ++r) { acc[r][0] = rd0; acc[r][1] = rd1; }

    // prefetch ch=0
    float4 nv0 = *(const float4*)(vb);
    float4 nv1 = *(const float4*)(vb + 512 * 4);
    float4 na0 = *(const float4*)(xlw);
    float4 na1 = *(const float4*)(xlw + Eq);
    float4 na2 = *(const float4*)(xlw + 2 * Eq);
    float4 na3 = *(const float4*)(xlw + 3 * Eq);
    float4 nat = *(const float4*)(att);

#pragma unroll
    for (int ch = 0; ch < 16; ++ch) {
      const float4 v0 = nv0, v1 = nv1;
      const float4 a0 = na0, a1 = na1, a2 = na2, a3 = na3, at = nat;
      if (ch < 15) {                      // issue ch+1 loads before computing ch
        vb += BN * 4;                     // next plane (+32 KB)
        nv0 = *(const float4*)(vb);
        nv1 = *(const float4*)(vb + 512 * 4);
        na0 = *(const float4*)(xlw + (ch + 1) * 4);
        na1 = *(const float4*)(xlw + Eq + (ch + 1) * 4);
        na2 = *(const float4*)(xlw + 2 * Eq + (ch + 1) * 4);
        na3 = *(const float4*)(xlw + 3 * Eq + (ch + 1) * 4);
        nat = *(const float4*)(att + (ch + 1) * 4);
      }
      const float* v0p = (const float*)&v0;
      const float* v1p = (const float*)&v1;
      const float* a0p = (const float*)&a0;
      const float* a1p = (const float*)&a1;
      const float* a2p = (const float*)&a2;
      const float* a3p = (const float*)&a3;
      const float* atp = (const float*)&at;
#pragma unroll
      for (int dd = 0; dd < 4; ++dd) {
        const float a = atp[dd];
        const float x0 = v0p[dd], x1 = v1p[dd];
        acc[0][0] = fmaf(fabsf(a0p[dd] + x0), a, acc[0][0]);
        acc[0][1] = fmaf(fabsf(a0p[dd] + x1), a, acc[0][1]);
        acc[1][0] = fmaf(fabsf(a1p[dd] + x0), a, acc[1][0]);
        acc[1][1] = fmaf(fabsf(a1p[dd] + x1), a, acc[1][1]);
        acc[2][0] = fmaf(fabsf(a2p[dd] + x0), a, acc[2][0]);
        acc[2][1] = fmaf(fabsf(a2p[dd] + x1), a, acc[2][1]);
        acc[3][0] = fmaf(fabsf(a3p[dd] + x0), a, acc[3][0]);
        acc[3][1] = fmaf(fabsf(a3p[dd] + x1), a, acc[3][1]);
      }
    }
#pragma unroll
    for (int r = 0; r < 4; ++r) {
      alpha[r0 + r][jt]       = acc[r][0];
      alpha[r0 + r][jt + 512] = acc[r][1];
    }
  }
  __syncthreads();

  // ---- phase 2: waves 0..7 = top-K of row `wave`, DPP-only reduces ----
  if (wave < TI) {
    float vals[16];
#pragma unroll
    for (int s = 0; s < 16; ++s) vals[s] = alpha[wave][lane + 64 * s];

    float lv = vals[0];
    int   pk = lane;                      // pk = (s<<6)|lane == j
#pragma unroll
    for (int s = 1; s < 16; ++s)
      if (vals[s] > lv) { lv = vals[s]; pk = (s << 6) | lane; }

    float m0 = 0.f, ssum = 0.f, myv = 0.f;
    int myi = 0;
#pragma unroll 1
    for (int round = 0; round < Kq; ++round) {
      float m = lv;
      m = fmaxf(m, DPP_F(m, QP_XOR1));
      m = fmaxf(m, DPP_F(m, QP_XOR2));
      m = fmaxf(m, DPP_F(m, ROR4));
      m = fmaxf(m, DPP_F(m, ROR8));
      const float bv = fmaxf(fmaxf(RL_F(m, 0), RL_F(m, 16)),
                             fmaxf(RL_F(m, 32), RL_F(m, 48)));
      int key = (lv == bv) ? pk : 0x7FFFFFFF;   // min-j tie-break (lax.top_k)
      key = min(key, DPP_I(key, QP_XOR1));
      key = min(key, DPP_I(key, QP_XOR2));
      key = min(key, DPP_I(key, ROR4));
      key = min(key, DPP_I(key, ROR8));
      const int jsel = min(min(RL_I(key, 0), RL_I(key, 16)),
                           min(RL_I(key, 32), RL_I(key, 48)));
      if (round == 0) m0 = bv;
      ssum += __expf(0.4f * (bv - m0));
      if (lane == round) { myv = bv; myi = jsel; }
      if (lane == (jsel & 63)) {          // owner knockout + rescan
        const int sk = jsel >> 6;
#pragma unroll
        for (int s = 0; s < 16; ++s)
          if (s == sk) vals[s] = NEGF;
        lv = vals[0]; pk = lane;
#pragma unroll
        for (int s = 1; s < 16; ++s)
          if (vals[s] > lv) { lv = vals[s]; pk = (s << 6) | lane; }
      }
    }

    if (lane < Kq) {
      const int gi = gi0 + wave;
      const float p = __expf(0.4f * (myv - m0)) / ssum;
      const int base = gi * Kq + lane;
      out[base]            = (float)gi;              // index_i
      out[BNK + base]      = (float)(b * Nq + myi);  // index_j
      out[2 * BNK + base]  = p;                      // attention
    }
  }
}

extern "C" void kernel_launch(void* const* d_in, const int* in_sizes, int n_in,
                              void* d_out, int out_size, void* d_ws, size_t ws_size,
                              hipStream_t stream) {
  const float* x   = (const float*)d_in[0];
  const float* Wl  = (const float*)d_in[1];
  const float* bl  = (const float*)d_in[2];
  const float* Wr  = (const float*)d_in[3];
  const float* br  = (const float*)d_in[4];
  const float* att = (const float*)d_in[5];
  float* out = (float*)d_out;

  float* xl   = (float*)d_ws;                    // [B*N, E]
  float* xrP  = xl + (size_t)BN * Eq;            // [16][B*N][4] plane-major packed
  float* rdot = xrP + (size_t)16 * BN * 4;       // [B*N]

  proj_kernel<<<BN, 128, 0, stream>>>(x, Wl, bl, Wr, br, att, xl, xrP, rdot);
  attn_kernel<<<BN / TI, 1024, 0, stream>>>(xl, xrP, rdot, att, out);
}